// Round 1
// baseline (419.427 us; speedup 1.0000x reference)
//
#include <hip/hip_runtime.h>

#define IN_DIM 98304
#define H1 256
#define H2 32
#define NZ_MAX 512

typedef float f32x4 __attribute__((ext_vector_type(4)));

__global__ __launch_bounds__(256) void nnue_fwd(
    const float* __restrict__ x,
    const float* __restrict__ W1,
    const float* __restrict__ b1,
    const float* __restrict__ W2,
    const float* __restrict__ b2,
    const float* __restrict__ Wout,
    const float* __restrict__ bout,
    float* __restrict__ out)
{
    __shared__ int   s_idx[NZ_MAX];
    __shared__ float s_val[NZ_MAX];
    __shared__ float s_h1[H1];
    __shared__ float s_h2[H2];
    __shared__ int   s_cnt;

    const int tid = threadIdx.x;
    const int row = blockIdx.x;

    if (tid == 0) s_cnt = 0;
    __syncthreads();

    // ---- Phase 1: scan the x row for nonzeros (nontemporal: don't evict W1 from L3) ----
    const f32x4* xr = reinterpret_cast<const f32x4*>(x + (size_t)row * IN_DIM);
    #pragma unroll 4
    for (int i = 0; i < IN_DIM / (256 * 4); ++i) {
        const int c4 = i * 256 + tid;          // float4 index within the row
        f32x4 v = __builtin_nontemporal_load(&xr[c4]);
        const int col = c4 * 4;
        if (v.x != 0.0f) { int p = atomicAdd(&s_cnt, 1); if (p < NZ_MAX) { s_idx[p] = col;     s_val[p] = v.x; } }
        if (v.y != 0.0f) { int p = atomicAdd(&s_cnt, 1); if (p < NZ_MAX) { s_idx[p] = col + 1; s_val[p] = v.y; } }
        if (v.z != 0.0f) { int p = atomicAdd(&s_cnt, 1); if (p < NZ_MAX) { s_idx[p] = col + 2; s_val[p] = v.z; } }
        if (v.w != 0.0f) { int p = atomicAdd(&s_cnt, 1); if (p < NZ_MAX) { s_idx[p] = col + 3; s_val[p] = v.w; } }
    }
    __syncthreads();

    int cnt = s_cnt;
    if (cnt > NZ_MAX) cnt = NZ_MAX;            // astronomically unlikely (Poisson(32) tail)
    const int cntp = (cnt + 7) & ~7;           // pad to multiple of 8 with zero terms
    if (tid < cntp - cnt) { s_idx[cnt + tid] = 0; s_val[cnt + tid] = 0.0f; }
    __syncthreads();

    // ---- Phase 2: h1[t] = relu(b1[t] + sum_k val[k] * W1[t][idx[k]]) ----
    {
        float acc = b1[tid];
        const float* w1r = W1 + (size_t)tid * IN_DIM;
        for (int k = 0; k < cntp; k += 8) {
            // 8 independent gathers (LDS idx/val reads broadcast: conflict-free)
            float a0 = s_val[k + 0] * w1r[s_idx[k + 0]];
            float a1 = s_val[k + 1] * w1r[s_idx[k + 1]];
            float a2 = s_val[k + 2] * w1r[s_idx[k + 2]];
            float a3 = s_val[k + 3] * w1r[s_idx[k + 3]];
            float a4 = s_val[k + 4] * w1r[s_idx[k + 4]];
            float a5 = s_val[k + 5] * w1r[s_idx[k + 5]];
            float a6 = s_val[k + 6] * w1r[s_idx[k + 6]];
            float a7 = s_val[k + 7] * w1r[s_idx[k + 7]];
            acc += ((a0 + a1) + (a2 + a3)) + ((a4 + a5) + (a6 + a7));
        }
        s_h1[tid] = fmaxf(acc, 0.0f);
    }
    __syncthreads();

    // ---- Phase 3: h2[j] = relu(b2[j] + W2[j,:] . h1)  (8 lanes per neuron) ----
    {
        const int j = tid >> 3;                // neuron 0..31
        const int p = tid & 7;                 // lane-part 0..7
        float part = 0.0f;
        // lane l reads W2[256*j + p + 8*k]: per iteration the wave touches 8
        // clusters of 8 consecutive floats -> 8 cache lines, L1/L2-resident.
        const float* w2r = W2 + j * H1 + p;
        #pragma unroll
        for (int k = 0; k < H1 / 8; ++k)
            part += w2r[8 * k] * s_h1[p + 8 * k];
        // reduce across the 8 parts (lanes 8j..8j+7 are contiguous in the wave)
        part += __shfl_xor(part, 1);
        part += __shfl_xor(part, 2);
        part += __shfl_xor(part, 4);
        if (p == 0) s_h2[j] = fmaxf(part + b2[j], 0.0f);
    }
    __syncthreads();

    // ---- Phase 4: out[row] = bout + Wout . h2 ----
    if (tid < 32) {
        float t = Wout[tid] * s_h2[tid];
        t += __shfl_xor(t, 1);
        t += __shfl_xor(t, 2);
        t += __shfl_xor(t, 4);
        t += __shfl_xor(t, 8);
        t += __shfl_xor(t, 16);
        if (tid == 0) out[row] = t + bout[0];
    }
}

extern "C" void kernel_launch(void* const* d_in, const int* in_sizes, int n_in,
                              void* d_out, int out_size, void* d_ws, size_t ws_size,
                              hipStream_t stream) {
    const float* x    = (const float*)d_in[0];
    const float* W1   = (const float*)d_in[1];
    const float* b1   = (const float*)d_in[2];
    const float* W2   = (const float*)d_in[3];
    const float* b2   = (const float*)d_in[4];
    const float* Wout = (const float*)d_in[5];
    const float* bout = (const float*)d_in[6];
    float* out = (float*)d_out;

    const int B = out_size;                    // 2048 rows, one block each
    nnue_fwd<<<B, 256, 0, stream>>>(x, W1, b1, W2, b2, Wout, bout, out);
}

// Round 2
// 177.649 us; speedup vs baseline: 2.3610x; 2.3610x over previous
//
#include <hip/hip_runtime.h>

#define IN_DIM 98304
#define H1 256
#define H2 32
#define NZ_MAX 512
#define TS 64

typedef float f32x4 __attribute__((ext_vector_type(4)));

// ---- Transpose W1 [H1][IN_DIM] -> W1T [IN_DIM][H1] (64x64 f32 tiles via LDS) ----
__global__ __launch_bounds__(256) void transpose_w1(const float* __restrict__ W1,
                                                    float* __restrict__ W1T) {
    __shared__ float tile[TS][TS + 4];     // [col][row], +4 keeps 16B alignment & breaks conflicts
    const int cb = blockIdx.x * TS;        // W1 column base
    const int rb = blockIdx.y * TS;        // W1 row base
    const int tx = threadIdx.x & 15;
    const int ty = threadIdx.x >> 4;       // 0..15

    #pragma unroll
    for (int rr = 0; rr < 4; ++rr) {
        const int r = rr * 16 + ty;        // 0..63
        f32x4 v = *reinterpret_cast<const f32x4*>(
            &W1[(size_t)(rb + r) * IN_DIM + cb + tx * 4]);
        tile[tx * 4 + 0][r] = v.x;
        tile[tx * 4 + 1][r] = v.y;
        tile[tx * 4 + 2][r] = v.z;
        tile[tx * 4 + 3][r] = v.w;
    }
    __syncthreads();
    #pragma unroll
    for (int cc = 0; cc < 4; ++cc) {
        const int c = cc * 16 + ty;        // W1 column = W1T row
        f32x4 v;
        v.x = tile[c][tx * 4 + 0];
        v.y = tile[c][tx * 4 + 1];
        v.z = tile[c][tx * 4 + 2];
        v.w = tile[c][tx * 4 + 3];
        *reinterpret_cast<f32x4*>(&W1T[(size_t)(cb + c) * H1 + rb + tx * 4]) = v;
    }
}

// ---- Fused NNUE forward: scan row -> sparse accum -> fc2 -> out ----
template <bool USE_T>
__global__ __launch_bounds__(256) void nnue_fwd(
    const float* __restrict__ x,
    const float* __restrict__ W1,      // row-major [H1][IN_DIM] (fallback)
    const float* __restrict__ W1T,     // transposed [IN_DIM][H1]
    const float* __restrict__ b1,
    const float* __restrict__ W2,
    const float* __restrict__ b2,
    const float* __restrict__ Wout,
    const float* __restrict__ bout,
    float* __restrict__ out)
{
    __shared__ int   s_idx[NZ_MAX];
    __shared__ float s_val[NZ_MAX];
    __shared__ float s_h1[H1];
    __shared__ float s_h2[H2];
    __shared__ int   s_cnt;

    const int tid = threadIdx.x;
    const int row = blockIdx.x;

    if (tid == 0) s_cnt = 0;
    __syncthreads();

    // ---- Phase 1: scan x row. 8 nontemporal f32x4 loads in flight, then test. ----
    const f32x4* xr = reinterpret_cast<const f32x4*>(x + (size_t)row * IN_DIM);
    for (int o = 0; o < IN_DIM / (256 * 4 * 8); ++o) {   // 12 outer iters
        f32x4 v[8];
        #pragma unroll
        for (int u = 0; u < 8; ++u)
            v[u] = __builtin_nontemporal_load(&xr[o * 2048 + u * 256 + tid]);
        #pragma unroll
        for (int u = 0; u < 8; ++u) {
            if (v[u].x != 0.0f || v[u].y != 0.0f || v[u].z != 0.0f || v[u].w != 0.0f) {
                const int col = (o * 2048 + u * 256 + tid) * 4;
                if (v[u].x != 0.0f) { int p = atomicAdd(&s_cnt, 1); if (p < NZ_MAX) { s_idx[p] = col;     s_val[p] = v[u].x; } }
                if (v[u].y != 0.0f) { int p = atomicAdd(&s_cnt, 1); if (p < NZ_MAX) { s_idx[p] = col + 1; s_val[p] = v[u].y; } }
                if (v[u].z != 0.0f) { int p = atomicAdd(&s_cnt, 1); if (p < NZ_MAX) { s_idx[p] = col + 2; s_val[p] = v[u].z; } }
                if (v[u].w != 0.0f) { int p = atomicAdd(&s_cnt, 1); if (p < NZ_MAX) { s_idx[p] = col + 3; s_val[p] = v[u].w; } }
            }
        }
    }
    __syncthreads();

    int cnt = s_cnt;
    if (cnt > NZ_MAX) cnt = NZ_MAX;
    const int cntp = (cnt + 3) & ~3;       // pad to multiple of 4 with zero terms
    if (tid < cntp - cnt) { s_idx[cnt + tid] = 0; s_val[cnt + tid] = 0.0f; }
    __syncthreads();

    // ---- Phase 2: h1[t] = relu(b1[t] + sum_k val[k] * W1[t][idx[k]]) ----
    {
        float acc = b1[tid];
        if (USE_T) {
            // coalesced: consecutive lanes read consecutive floats of W1T row idx
            for (int k = 0; k < cntp; k += 4) {
                const int   i0 = s_idx[k + 0], i1 = s_idx[k + 1], i2 = s_idx[k + 2], i3 = s_idx[k + 3];
                const float c0 = s_val[k + 0], c1 = s_val[k + 1], c2 = s_val[k + 2], c3 = s_val[k + 3];
                const float a0 = W1T[(size_t)i0 * H1 + tid];
                const float a1 = W1T[(size_t)i1 * H1 + tid];
                const float a2 = W1T[(size_t)i2 * H1 + tid];
                const float a3 = W1T[(size_t)i3 * H1 + tid];
                acc += (c0 * a0 + c1 * a1) + (c2 * a2 + c3 * a3);
            }
        } else {
            const float* w1r = W1 + (size_t)tid * IN_DIM;
            for (int k = 0; k < cntp; k += 4) {
                const float a0 = s_val[k + 0] * w1r[s_idx[k + 0]];
                const float a1 = s_val[k + 1] * w1r[s_idx[k + 1]];
                const float a2 = s_val[k + 2] * w1r[s_idx[k + 2]];
                const float a3 = s_val[k + 3] * w1r[s_idx[k + 3]];
                acc += (a0 + a1) + (a2 + a3);
            }
        }
        s_h1[tid] = fmaxf(acc, 0.0f);
    }
    __syncthreads();

    // ---- Phase 3: h2[j] = relu(b2[j] + W2[j,:] . h1)  (8 lanes per neuron) ----
    {
        const int j = tid >> 3;
        const int p = tid & 7;
        float part = 0.0f;
        const float* w2r = W2 + j * H1 + p;
        #pragma unroll
        for (int k = 0; k < H1 / 8; ++k)
            part += w2r[8 * k] * s_h1[p + 8 * k];
        part += __shfl_xor(part, 1);
        part += __shfl_xor(part, 2);
        part += __shfl_xor(part, 4);
        if (p == 0) s_h2[j] = fmaxf(part + b2[j], 0.0f);
    }
    __syncthreads();

    // ---- Phase 4: out[row] = bout + Wout . h2 ----
    if (tid < 32) {
        float t = Wout[tid] * s_h2[tid];
        t += __shfl_xor(t, 1);
        t += __shfl_xor(t, 2);
        t += __shfl_xor(t, 4);
        t += __shfl_xor(t, 8);
        t += __shfl_xor(t, 16);
        if (tid == 0) out[row] = t + bout[0];
    }
}

extern "C" void kernel_launch(void* const* d_in, const int* in_sizes, int n_in,
                              void* d_out, int out_size, void* d_ws, size_t ws_size,
                              hipStream_t stream) {
    const float* x    = (const float*)d_in[0];
    const float* W1   = (const float*)d_in[1];
    const float* b1   = (const float*)d_in[2];
    const float* W2   = (const float*)d_in[3];
    const float* b2   = (const float*)d_in[4];
    const float* Wout = (const float*)d_in[5];
    const float* bout = (const float*)d_in[6];
    float* out = (float*)d_out;

    const int B = out_size;                         // 2048 rows
    const size_t w1t_bytes = (size_t)IN_DIM * H1 * sizeof(float);  // ~100.7 MB

    if (ws_size >= w1t_bytes) {
        float* W1T = (float*)d_ws;
        transpose_w1<<<dim3(IN_DIM / TS, H1 / TS), 256, 0, stream>>>(W1, W1T);
        nnue_fwd<true><<<B, 256, 0, stream>>>(x, W1, W1T, b1, W2, b2, Wout, bout, out);
    } else {
        nnue_fwd<false><<<B, 256, 0, stream>>>(x, W1, nullptr, b1, W2, b2, Wout, bout, out);
    }
}